// Round 4
// baseline (154.691 us; speedup 1.0000x reference)
//
#include <hip/hip_runtime.h>

#define VOCAB 50000
#define EMBED 256
#define NB    16
#define NC    64
#define NS    512
#define UNK   1

// ---- bf16 fast path (R11): XCD-partitioned gathers, lean entry processing ----
// R10 post-mortem: partitioning worked on the traffic axis (FETCH 141->32 MB,
// table fetched ~once) but per-entry cost exploded (14 DS ops / 2 rows: 5
// shuffles + 2 LDS atomics + serialized cnt atomics) -> 45 us, VALU 36%,
// nothing memory-bound. R11 keeps the (b, jt, partition) worklist but:
//  - 4 lanes per entry, 16 entries per wave-iter: 8x uint4 gather + 8x
//    ds_read_b128 from a 528-B-padded q table; reduction = 2 width-4
//    shuffles + 1 LDS atomic per 16 entries (DS/entry 7 -> 0.75).
//  - ballot-aggregated worklist append (1 atomic per wave-instr).
//  - per-lane cache lines are private across the 8 k-steps -> L1 hits.
#define NPART 8
#define PDIV  ((VOCAB + NPART - 1) / NPART)   // 6250 rows per partition (3.2 MB slice)
#define PJT   8                               // j tiles
#define PJLEN 64                              // j's per tile
#define WLCAP 1024                            // worklist cap (mean 512, sigma 21 -> 24-sigma safe)
#define QSTRIDE 528                           // padded bf16 q-row stride (odd multiple of 16 B)
#define NSLICE (NPART * PJT)                  // 64 partial slices
#define BF_TABLE_BYTES ((size_t)VOCAB * EMBED * 2)          // 25,600,000
#define PARTIAL_ELEMS  (NSLICE * NB * NC)                   // 65536

__device__ __forceinline__ unsigned short f2bf_rne(float f) {
    unsigned int u = __float_as_uint(f);
    u = (u + 0x7fffu + ((u >> 16) & 1u)) >> 16;             // round-nearest-even
    return (unsigned short)u;
}

// Stream-convert emb f32 -> bf16 table in ws. 400k threads x 8 elems.
__global__ __launch_bounds__(256) void convert_kernel(
    const float* __restrict__ emb, unsigned int* __restrict__ bf)
{
    const size_t t = (size_t)blockIdx.x * 256 + threadIdx.x;
    const float4* __restrict__ e4 = (const float4*)emb;
    const float4 a = e4[t * 2];
    const float4 b = e4[t * 2 + 1];
    uint4 r;
    r.x = (unsigned int)f2bf_rne(a.x) | ((unsigned int)f2bf_rne(a.y) << 16);
    r.y = (unsigned int)f2bf_rne(a.z) | ((unsigned int)f2bf_rne(a.w) << 16);
    r.z = (unsigned int)f2bf_rne(b.x) | ((unsigned int)f2bf_rne(b.y) << 16);
    r.w = (unsigned int)f2bf_rne(b.z) | ((unsigned int)f2bf_rne(b.w) << 16);
    ((uint4*)bf)[t] = r;
}

__device__ __forceinline__ float dot_u(unsigned a, unsigned b) {
    const float a0 = __uint_as_float(a << 16);
    const float a1 = __uint_as_float(a & 0xffff0000u);
    const float b0 = __uint_as_float(b << 16);
    const float b1 = __uint_as_float(b & 0xffff0000u);
    return a0 * b0 + a1 * b1;
}

// Grid = NB * PJT * NPART = 1024 blocks, 256 threads.
// Block (b, jt, p): filter the tile's 4096 ids down to partition p's entries,
// gather only partition-local rows (XCD-local L2), 4 lanes per entry.
__global__ __launch_bounds__(256) void scores_part_kernel(
    const int* __restrict__ src, const int* __restrict__ q,
    const unsigned int* __restrict__ bf, float* __restrict__ partial)
{
    const int bid = blockIdx.x;
    const int p   = bid & (NPART - 1);          // -> XCD p (round-robin dispatch)
    const int jt  = (bid >> 3) & (PJT - 1);
    const int b   = bid >> 6;
    const int j0  = jt * PJLEN;

    const int tid  = threadIdx.x;
    const int wave = tid >> 6;
    const int lane = tid & 63;
    const int sub  = lane & 3;                  // 128-B slice of the row

    const uint4* __restrict__ bft4 = (const uint4*)bf;      // 32 x 16 B per row

    __shared__ unsigned char qt_raw[PJLEN * QSTRIDE];       // 33792 B padded bf16 q rows
    __shared__ unsigned int wl[WLCAP];          // 4 KB packed (sid<<12)|(c<<6)|jj
    __shared__ float score_sh[NC];              // 256 B
    __shared__ int qid_sh[PJLEN];
    __shared__ int cnt;

    if (tid < PJLEN) {
        const int qv = q[(size_t)b * NS + j0 + tid];
        qid_sh[tid] = (qv == 0) ? -1 : ((qv >= VOCAB) ? UNK : qv);
    }
    if (tid < NC) score_sh[tid] = 0.f;
    if (tid == 0) cnt = 0;
    __syncthreads();

    // stage q rows (bf16) into padded LDS: 64 rows x 32 cols of 16 B, 8/thread.
    // Coalesced 512-B global reads; ds_write_b128 quad = (row+col)%8 -> even.
#pragma unroll
    for (int i = 0; i < 8; i++) {
        const int idx = i * 256 + tid;
        const int row = idx >> 5;
        const int col = idx & 31;
        const int qid = qid_sh[row];
        if (qid >= 0) {
            const uint4 v = bft4[(size_t)qid * 32 + col];
            *(uint4*)(qt_raw + row * QSTRIDE + col * 16) = v;
        }
    }

    // filter 4096 ids -> worklist; ballot-aggregated append (1 atomic/wave-instr).
    // A wave-instr covers one c with jj = 0..63 -> wl runs have consecutive j.
    const int lo = p * PDIV;
    const int* __restrict__ srow = src + (size_t)b * NC * NS;
#pragma unroll
    for (int k = 0; k < 16; k++) {
        const int idx = k * 256 + tid;          // = c*64 + jj
        const int c   = idx >> 6;
        const int jj  = idx & 63;
        int sv = srow[(size_t)c * NS + j0 + jj];
        sv = (sv >= VOCAB) ? UNK : sv;
        const bool take = (qid_sh[jj] >= 0) && ((unsigned)(sv - lo) < (unsigned)PDIV);
        const unsigned long long bal = __ballot(take);
        int base = 0;
        if (lane == 0 && bal != 0ull) base = atomicAdd(&cnt, __popcll(bal));
        base = __shfl(base, 0, 64);
        if (take) {
            const int pos = base + __popcll(bal & ((1ull << lane) - 1ull));
            if (pos < WLCAP)
                wl[pos] = ((unsigned)sv << 12) | (unsigned)(c << 6) | (unsigned)jj;
        }
    }
    __syncthreads();

    const int nE = (cnt < WLCAP) ? cnt : WLCAP;

    // main loop: 16 entries per wave-iter, 4 lanes per entry (128 B/lane).
    // Per iter: 1 wl b32 + 8 qt b128 + 8 uint4 gathers + 2 shfl + 1 atomic.
    for (int e0 = wave * 16; e0 < nE; e0 += 64) {
        const int e = e0 + (lane >> 2);
        const bool valid = e < nE;
        const unsigned w = wl[valid ? e : 0];
        const int sid = (int)(w >> 12);
        const int c   = (int)((w >> 6) & 63u);
        const int j   = (int)(w & 63u);
        const uint4* __restrict__ grow = bft4 + (size_t)sid * 32 + sub * 8;
        const unsigned char* qbase = qt_raw + j * QSTRIDE + sub * 128;
        float acc = 0.f;
#pragma unroll
        for (int k = 0; k < 8; k++) {
            const uint4 g  = grow[k];                        // L1-resident after k=0
            const uint4 qv = *(const uint4*)(qbase + k * 16);
            acc += dot_u(g.x, qv.x) + dot_u(g.y, qv.y)
                 + dot_u(g.z, qv.z) + dot_u(g.w, qv.w);
        }
        acc += __shfl_down(acc, 2, 4);                       // reduce 4-lane group
        acc += __shfl_down(acc, 1, 4);
        if (valid && sub == 0) atomicAdd(&score_sh[c], acc);
    }
    __syncthreads();

    if (tid < NC)
        partial[(size_t)(p * PJT + jt) * (NB * NC) + b * NC + tid] = score_sh[tid];
}

// ---- f32 fallback (proven R5 path), JT=8/JLEN=64, CTILE=8 ----
__global__ __launch_bounds__(256) void scores_f32_kernel(
    const int* __restrict__ src, const int* __restrict__ q,
    const float* __restrict__ emb, float* __restrict__ partial)
{
    const int x  = blockIdx.x;
    const int jt = x & 7;
    const int ct = (x >> 3) & 7;
    const int b  = x >> 6;
    const int c0 = ct * 8;
    const int j0 = jt * 64;

    const int tid = threadIdx.x, wave = tid >> 6, lane = tid & 63;
    const float4* __restrict__ emb4 = (const float4*)emb;
    const int* __restrict__ qrow = q + (size_t)b * NS;
    const int* __restrict__ srow = src + ((size_t)b * NC + c0) * NS;

    float acc[8];
#pragma unroll
    for (int i = 0; i < 8; i++) acc[i] = 0.f;

    for (int j = j0 + wave; j < j0 + 64; j += 4) {
        const int qv = qrow[j];
        if (qv > 0) {
            const int qid = (qv >= VOCAB) ? UNK : qv;
            const float4 eq = emb4[(size_t)qid * (EMBED / 4) + lane];
            float4 a[8];
#pragma unroll
            for (int i = 0; i < 8; i++) {
                const int sv = srow[(size_t)i * NS + j];
                a[i] = emb4[(size_t)((sv >= VOCAB) ? UNK : sv) * (EMBED / 4) + lane];
            }
#pragma unroll
            for (int i = 0; i < 8; i++)
                acc[i] += a[i].x * eq.x + a[i].y * eq.y + a[i].z * eq.z + a[i].w * eq.w;
        }
    }
#pragma unroll
    for (int off = 32; off > 0; off >>= 1)
#pragma unroll
        for (int i = 0; i < 8; i++)
            acc[i] += __shfl_down(acc[i], off, 64);

    __shared__ float red[4][8];
    if (lane == 0)
#pragma unroll
        for (int i = 0; i < 8; i++) red[wave][i] = acc[i];
    __syncthreads();
    if (tid < 8)
        partial[(size_t)jt * (NB * NC) + b * NC + c0 + tid] =
            red[0][tid] + red[1][tid] + red[2][tid] + red[3][tid];
}

// One block per b. Wave 0: sum jtn partials -> softmax -> sims + argmax;
// then all 256 threads copy the winning source row as f32.
__global__ __launch_bounds__(256) void finalize_kernel(
    const float* __restrict__ partial, const int* __restrict__ src,
    float* __restrict__ out, int jtn)
{
    const int b = blockIdx.x, tid = threadIdx.x;
    __shared__ int top_sh;

    if (tid < 64) {
        float s = 0.f;
        for (int t = 0; t < jtn; t++)
            s += partial[(size_t)t * (NB * NC) + b * NC + tid];

        float m = s;
#pragma unroll
        for (int off = 32; off > 0; off >>= 1)
            m = fmaxf(m, __shfl_xor(m, off, 64));
        const float e = expf(s - m);
        float sum = e;
#pragma unroll
        for (int off = 32; off > 0; off >>= 1)
            sum += __shfl_xor(sum, off, 64);

        out[NB * NS + b * NC + tid] = e / sum;       // sims after 8192 ids

        const unsigned long long ballot = __ballot(s == m);
        if (tid == 0) top_sh = __ffsll(ballot) - 1;  // first occurrence
    }
    __syncthreads();

    const int top = top_sh;
    const int* __restrict__ srow = src + ((size_t)b * NC + top) * NS;
    for (int j = tid; j < NS; j += 256)
        out[b * NS + j] = (float)srow[j];
}

extern "C" void kernel_launch(void* const* d_in, const int* in_sizes, int n_in,
                              void* d_out, int out_size, void* d_ws, size_t ws_size,
                              hipStream_t stream) {
    const int*   src = (const int*)d_in[0];    // [NB*NC, NS] int32
    const int*   q   = (const int*)d_in[1];    // [NB, NS] int32
    const float* emb = (const float*)d_in[3];  // [VOCAB, EMBED] f32
    float* out = (float*)d_out;                // 8192 out_sources + 1024 sims (f32)

    if (ws_size >= BF_TABLE_BYTES + PARTIAL_ELEMS * sizeof(float)) {
        unsigned int* bf = (unsigned int*)d_ws;
        float* partial = (float*)((char*)d_ws + BF_TABLE_BYTES);
        convert_kernel<<<VOCAB * EMBED / 2048, 256, 0, stream>>>(emb, bf);
        scores_part_kernel<<<NB * PJT * NPART, 256, 0, stream>>>(src, q, bf, partial);
        finalize_kernel<<<NB, 256, 0, stream>>>(partial, src, out, NSLICE);
    } else {
        float* partial = (float*)d_ws;         // 8192 floats
        scores_f32_kernel<<<NB * 8 * 8, 256, 0, stream>>>(src, q, emb, partial);
        finalize_kernel<<<NB, 256, 0, stream>>>(partial, src, out, 8);
    }
}

// Round 5
// 128.521 us; speedup vs baseline: 1.2036x; 1.2036x over previous
//
#include <hip/hip_runtime.h>

#define VOCAB 50000
#define EMBED 256
#define NB    16
#define NC    64
#define NS    512
#define UNK   1

// ---- bf16 fast path (R12): R0 inner loop + occupancy-directed geometry ----
// R10/R11 closed the partition branch: FETCH 141->32 MB proved the traffic
// thesis but worklist/indirection overhead (50 us, 1.7M bank conflicts) lost
// to the simple kernel. R0 re-analysis: scores saturates nothing (per-CU
// 14 B/cy vs 60 L2 ceiling, VALU 11%) and the 1024-block grid caps occupancy
// at 4 blocks/CU = 16 waves. Also: R0's 32 KB qt LDS staging was a no-op --
// wave w staged rows {w, w+4,..} and only wave w read them back. R12:
//  - this wave's 8 q rows live in 16 VGPRs (bf16, static unroll, no LDS);
//  - CTILE 16->8 -> 2048 blocks -> 8 blocks/CU reachable; VGPR ~55 keeps
//    8 waves/SIMD without __launch_bounds__ min-wave coercion (R8/R9 trap).
// Spill sentinel: scores WRITE_SIZE must stay ~0.07 MB.
#define CTILE 8               // c's per block
#define JT    16              // j tiles
#define JLEN  (NS / JT)       // 32 j's per tile
#define BF_TABLE_BYTES ((size_t)VOCAB * EMBED * 2)          // 25,600,000
#define PARTIAL_ELEMS  (JT * NB * NC)                       // 16384

__device__ __forceinline__ unsigned short f2bf_rne(float f) {
    unsigned int u = __float_as_uint(f);
    u = (u + 0x7fffu + ((u >> 16) & 1u)) >> 16;             // round-nearest-even
    return (unsigned short)u;
}

// Stream-convert emb f32 -> bf16 table in ws. 400k threads x 8 elems.
__global__ __launch_bounds__(256) void convert_kernel(
    const float* __restrict__ emb, unsigned int* __restrict__ bf)
{
    const size_t t = (size_t)blockIdx.x * 256 + threadIdx.x;
    const float4* __restrict__ e4 = (const float4*)emb;
    const float4 a = e4[t * 2];
    const float4 b = e4[t * 2 + 1];
    uint4 r;
    r.x = (unsigned int)f2bf_rne(a.x) | ((unsigned int)f2bf_rne(a.y) << 16);
    r.y = (unsigned int)f2bf_rne(a.z) | ((unsigned int)f2bf_rne(a.w) << 16);
    r.z = (unsigned int)f2bf_rne(b.x) | ((unsigned int)f2bf_rne(b.y) << 16);
    r.w = (unsigned int)f2bf_rne(b.z) | ((unsigned int)f2bf_rne(b.w) << 16);
    ((uint4*)bf)[t] = r;
}

// Gather-bound scores. Grid = NB * (NC/CTILE) * JT = 2048 blocks, 256 thr.
// Wave w owns j = w, w+4, ... (8 iters); its q rows are preloaded into 16
// VGPRs. Per iter: 8 full-row uint2 gathers (64 lanes x 8 B = one 512-B row
// per instruction, fully coalesced) + 64 unpack/FMA VALU ops.
__global__ __launch_bounds__(256) void scores_bf_kernel(
    const int* __restrict__ src, const int* __restrict__ q,
    const unsigned int* __restrict__ bf, float* __restrict__ partial)
{
    const int x  = blockIdx.x;
    const int jt = x & (JT - 1);
    const int ct = (x >> 4) & (NC / CTILE - 1);
    const int b  = x >> 7;
    const int c0 = ct * CTILE;
    const int j0 = jt * JLEN;

    const int tid  = threadIdx.x;
    const int wave = tid >> 6;
    const int lane = tid & 63;          // covers row bytes [8*lane, 8*lane+8)

    const uint2* __restrict__ bfe = (const uint2*)bf;       // 64 uint2 per row
    const int* __restrict__ qrow = q + (size_t)b * NS;
    const int* __restrict__ srow = src + ((size_t)b * NC + c0) * NS;

    __shared__ int sids[CTILE][JLEN];   // 1 KB clamped source ids
    __shared__ int qids[JLEN];
    __shared__ int nnz_sh;

    if (tid < 64) {                                  // wave 0
        const int qv = (tid < JLEN) ? qrow[j0 + tid] : 0;
        if (tid < JLEN) qids[tid] = (qv >= VOCAB) ? UNK : qv;
        const unsigned long long bal = __ballot(qv > 0);
        if (tid == 0) nnz_sh = __popcll(bal);        // contiguous prefix in tile
    }
    {   // 256 tile ids, 1 per thread, coalesced
        const int i  = tid >> 5;        // c within tile (0..7)
        const int j  = tid & (JLEN - 1);
        const int sv = srow[(size_t)i * NS + j0 + j];
        sids[i][j] = (sv >= VOCAB) ? UNK : sv;
    }
    __syncthreads();

    const int nnz = nnz_sh;

    // preload this wave's q rows (bf16) into registers: j = wave + 4*it.
    // Static indexing only (rule: runtime-indexed arrays spill to scratch).
    uint2 qr[8];
#pragma unroll
    for (int it = 0; it < 8; ++it) {
        const int j = wave + it * 4;
        qr[it] = (j < nnz) ? bfe[(size_t)qids[j] * 64 + lane]
                           : make_uint2(0u, 0u);
    }

    float acc[CTILE];
#pragma unroll
    for (int i = 0; i < CTILE; i++) acc[i] = 0.f;

#pragma unroll
    for (int it = 0; it < 8; ++it) {
        const int j = wave + it * 4;
        if (j >= nnz) break;            // nnz block-uniform, j wave-uniform
        const float q0 = __uint_as_float(qr[it].x << 16);
        const float q1 = __uint_as_float(qr[it].x & 0xffff0000u);
        const float q2 = __uint_as_float(qr[it].y << 16);
        const float q3 = __uint_as_float(qr[it].y & 0xffff0000u);
        uint2 g[CTILE];
#pragma unroll
        for (int i = 0; i < CTILE; i++)
            g[i] = bfe[(size_t)sids[i][j] * 64 + lane];     // 512-B row/instr
#pragma unroll
        for (int i = 0; i < CTILE; i++) {
            const float f0 = __uint_as_float(g[i].x << 16);
            const float f1 = __uint_as_float(g[i].x & 0xffff0000u);
            const float f2 = __uint_as_float(g[i].y << 16);
            const float f3 = __uint_as_float(g[i].y & 0xffff0000u);
            acc[i] += f0 * q0 + f1 * q1 + f2 * q2 + f3 * q3;
        }
    }

#pragma unroll
    for (int off = 32; off > 0; off >>= 1)
#pragma unroll
        for (int i = 0; i < CTILE; i++)
            acc[i] += __shfl_down(acc[i], off, 64);

    __shared__ float red[4][CTILE];
    if (lane == 0)
#pragma unroll
        for (int i = 0; i < CTILE; i++) red[wave][i] = acc[i];
    __syncthreads();

    if (tid < CTILE) {
        const float s = red[0][tid] + red[1][tid] + red[2][tid] + red[3][tid];
        partial[(size_t)jt * (NB * NC) + b * NC + c0 + tid] = s;
    }
}

// ---- f32 fallback (proven R5 path), JT=8/JLEN=64, CTILE=8 ----
__global__ __launch_bounds__(256) void scores_f32_kernel(
    const int* __restrict__ src, const int* __restrict__ q,
    const float* __restrict__ emb, float* __restrict__ partial)
{
    const int x  = blockIdx.x;
    const int jt = x & 7;
    const int ct = (x >> 3) & 7;
    const int b  = x >> 6;
    const int c0 = ct * 8;
    const int j0 = jt * 64;

    const int tid = threadIdx.x, wave = tid >> 6, lane = tid & 63;
    const float4* __restrict__ emb4 = (const float4*)emb;
    const int* __restrict__ qrow = q + (size_t)b * NS;
    const int* __restrict__ srow = src + ((size_t)b * NC + c0) * NS;

    float acc[8];
#pragma unroll
    for (int i = 0; i < 8; i++) acc[i] = 0.f;

    for (int j = j0 + wave; j < j0 + 64; j += 4) {
        const int qv = qrow[j];
        if (qv > 0) {
            const int qid = (qv >= VOCAB) ? UNK : qv;
            const float4 eq = emb4[(size_t)qid * (EMBED / 4) + lane];
            float4 a[8];
#pragma unroll
            for (int i = 0; i < 8; i++) {
                const int sv = srow[(size_t)i * NS + j];
                a[i] = emb4[(size_t)((sv >= VOCAB) ? UNK : sv) * (EMBED / 4) + lane];
            }
#pragma unroll
            for (int i = 0; i < 8; i++)
                acc[i] += a[i].x * eq.x + a[i].y * eq.y + a[i].z * eq.z + a[i].w * eq.w;
        }
    }
#pragma unroll
    for (int off = 32; off > 0; off >>= 1)
#pragma unroll
        for (int i = 0; i < 8; i++)
            acc[i] += __shfl_down(acc[i], off, 64);

    __shared__ float red[4][8];
    if (lane == 0)
#pragma unroll
        for (int i = 0; i < 8; i++) red[wave][i] = acc[i];
    __syncthreads();
    if (tid < 8)
        partial[(size_t)jt * (NB * NC) + b * NC + c0 + tid] =
            red[0][tid] + red[1][tid] + red[2][tid] + red[3][tid];
}

// One block per b. Wave 0: sum jtn partials -> softmax -> sims + argmax;
// then all 256 threads copy the winning source row as f32.
__global__ __launch_bounds__(256) void finalize_kernel(
    const float* __restrict__ partial, const int* __restrict__ src,
    float* __restrict__ out, int jtn)
{
    const int b = blockIdx.x, tid = threadIdx.x;
    __shared__ int top_sh;

    if (tid < 64) {
        float s = 0.f;
        for (int t = 0; t < jtn; t++)
            s += partial[(size_t)t * (NB * NC) + b * NC + tid];

        float m = s;
#pragma unroll
        for (int off = 32; off > 0; off >>= 1)
            m = fmaxf(m, __shfl_xor(m, off, 64));
        const float e = expf(s - m);
        float sum = e;
#pragma unroll
        for (int off = 32; off > 0; off >>= 1)
            sum += __shfl_xor(sum, off, 64);

        out[NB * NS + b * NC + tid] = e / sum;       // sims after 8192 ids

        const unsigned long long ballot = __ballot(s == m);
        if (tid == 0) top_sh = __ffsll(ballot) - 1;  // first occurrence
    }
    __syncthreads();

    const int top = top_sh;
    const int* __restrict__ srow = src + ((size_t)b * NC + top) * NS;
    for (int j = tid; j < NS; j += 256)
        out[b * NS + j] = (float)srow[j];
}

extern "C" void kernel_launch(void* const* d_in, const int* in_sizes, int n_in,
                              void* d_out, int out_size, void* d_ws, size_t ws_size,
                              hipStream_t stream) {
    const int*   src = (const int*)d_in[0];    // [NB*NC, NS] int32
    const int*   q   = (const int*)d_in[1];    // [NB, NS] int32
    const float* emb = (const float*)d_in[3];  // [VOCAB, EMBED] f32
    float* out = (float*)d_out;                // 8192 out_sources + 1024 sims (f32)

    if (ws_size >= BF_TABLE_BYTES + PARTIAL_ELEMS * sizeof(float)) {
        unsigned int* bf = (unsigned int*)d_ws;
        float* partial = (float*)((char*)d_ws + BF_TABLE_BYTES);
        convert_kernel<<<VOCAB * EMBED / 2048, 256, 0, stream>>>(emb, bf);
        scores_bf_kernel<<<NB * (NC / CTILE) * JT, 256, 0, stream>>>(src, q, bf, partial);
        finalize_kernel<<<NB, 256, 0, stream>>>(partial, src, out, JT);
    } else {
        float* partial = (float*)d_ws;         // 8192 floats
        scores_f32_kernel<<<NB * 8 * 8, 256, 0, stream>>>(src, q, emb, partial);
        finalize_kernel<<<NB, 256, 0, stream>>>(partial, src, out, 8);
    }
}